// Round 13
// baseline (57.906 us; speedup 1.0000x reference)
//
#include <hip/hip_runtime.h>

// ConvCapsuleLayer r13: BARRIER-FREE routing. One wave owns one w-position
// (all 256 ch); routing runs entirely in registers + wave shuffles.
// Lane owns 4 ch (ch = lane*4+j): c = lane>>3 uniform, atoms 4*(lane&7)+j.
// Votes cross waves once via LDS [w][grp 64][68B] (stride-68 -> <=2-way banks).
// Conv = r11 form (fp16 MFMA 32x32x16, M=32 x N=256 per 256-thr block).

typedef __attribute__((ext_vector_type(2))) _Float16 f16x2;
typedef __attribute__((ext_vector_type(8))) _Float16 f16x8;
typedef __attribute__((ext_vector_type(16))) float f32x16;

union f16x8u { f16x8 v; f16x2 d[4]; unsigned short s[8]; unsigned int u32[4]; unsigned long long u[2]; };
union f16x2u { f16x2 v; unsigned int u; unsigned short s[2]; };

__device__ __forceinline__ unsigned short f2h(float x) {
  union { _Float16 h; unsigned short u; } v;
  v.h = (_Float16)x;
  return v.u;
}

// W[5][5][16][256] f32 -> wsh fp16 [khkw 25][ch 256][ia 16]
__global__ __launch_bounds__(256) void wprep_kernel(
    const float* __restrict__ W, unsigned short* __restrict__ wsh) {
  int t = blockIdx.x * 256 + threadIdx.x;      // 102400 total
  int khkw = t >> 12;
  int rem  = t & 4095;
  int ch = rem >> 4, ia = rem & 15;
  wsh[t] = f2h(W[khkw * 4096 + ia * 256 + ch]);
}

// LDS map (17408 B):
//   conv phase:  X fp16 [kh 5][ii 8, stride 272B][wl 8][ia 16] = 10880 B @0
//   transpose:   votesT fp16 [w 4, stride 4352][grp 64, stride 68][j 4][ii 8] @0
//                (aliases X; stride 68B -> bank stride 17, gcd(17,32)=1 -> <=2-way)
__global__ __launch_bounds__(256, 2) void capsconv_mfma_kernel(
    const float* __restrict__ inp,            // [16][32][32][8][16] f32
    const unsigned short* __restrict__ wsh,   // [25][256][16] fp16
    const float* __restrict__ bias,           // [256] f32
    float* __restrict__ out)                  // [16][32][32][256] f32
{
  __shared__ char smem[17408];
  const _Float16* wshh = (const _Float16*)wsh;

  const int tid  = threadIdx.x;
  const int wid  = tid >> 6;          // wave 0..3: conv ch quarter; routing w
  const int lane = tid & 63;
  const int sub  = lane >> 5;
  const int ln31 = lane & 31;

  const int bid = blockIdx.x;         // 4096 = ((bb*32 + h)*8 + wq)
  const int wq = bid & 7;
  const int h  = (bid >> 3) & 31;
  const int bb = bid >> 8;
  const int i_src  = bb >> 1;         // TF reshape scramble (verified r1/r4)
  const int b_base = (bb & 1) * 8;

  // ---------------- stage 5 X rows, PO2 decode (1280 quads) ----------------
  #pragma unroll
  for (int s = 0; s < 5; ++s) {
    int e = tid + s * 256;
    int kh  = e >> 8;
    int ii  = (e >> 5) & 7;
    int wl  = (e >> 2) & 7;
    int iaq = e & 3;
    int hh = h + kh - 2;
    int wsrc = wq * 4 + wl - 2;
    float4 v = make_float4(0.f, 0.f, 0.f, 0.f);
    if ((unsigned)hh < 32u && (unsigned)wsrc < 32u)
      v = *(const float4*)(inp +
          ((((size_t)(b_base + ii) * 32 + hh) * 32 + wsrc) * 8 + i_src) * 16 + iaq * 4);
    union { _Float16 hx[4]; unsigned long long u; } pkk;
    pkk.hx[0] = (_Float16)v.x; pkk.hx[1] = (_Float16)v.y;
    pkk.hx[2] = (_Float16)v.z; pkk.hx[3] = (_Float16)v.w;
    *(unsigned long long*)(smem + kh * 2176 + ii * 272 + wl * 32 + iaq * 8) = pkk.u;
  }
  __syncthreads();

  // ---------------- conv: 25 taps (r11 form) ----------------
  f32x16 acc[2];
  #pragma unroll
  for (int nt = 0; nt < 2; ++nt)
    #pragma unroll
    for (int e = 0; e < 16; ++e) acc[nt][e] = 0.f;

  const char* aBase = smem + (ln31 & 7) * 272 + (ln31 >> 3) * 32 + sub * 16;
  const _Float16* bBase = wshh + (wid * 64 + ln31) * 16 + sub * 8;

  #pragma unroll
  for (int kh = 0; kh < 5; ++kh) {
    f16x8 af[5], bf0[5], bf1[5];
    #pragma unroll
    for (int kw = 0; kw < 5; ++kw) {
      af[kw]  = *(const f16x8*)(aBase + kh * 2176 + kw * 32);
      bf0[kw] = *(const f16x8*)(bBase + (size_t)(kh * 5 + kw) * 4096);
      bf1[kw] = *(const f16x8*)(bBase + (size_t)(kh * 5 + kw) * 4096 + 512);
    }
    #pragma unroll
    for (int kw = 0; kw < 5; ++kw) {
      acc[0] = __builtin_amdgcn_mfma_f32_32x32x16_f16(af[kw], bf0[kw], acc[0], 0, 0, 0);
      acc[1] = __builtin_amdgcn_mfma_f32_32x32x16_f16(af[kw], bf1[kw], acc[1], 0, 0, 0);
    }
  }

  // ---------------- pack acc -> fp16; assemble vreg via lane^32 shfl ----------------
  // acc[nt][w*4+t] = vote(w, ii=t+4sub, ch=wid*64+nt*32+ln31); lanes L,L^32 share ch set.
  unsigned int pk[2][4][2];
  #pragma unroll
  for (int nt = 0; nt < 2; ++nt)
    #pragma unroll
    for (int w = 0; w < 4; ++w) {
      f16x2u lo, hi;
      lo.v = f16x2{(_Float16)acc[nt][w * 4 + 0], (_Float16)acc[nt][w * 4 + 1]};
      hi.v = f16x2{(_Float16)acc[nt][w * 4 + 2], (_Float16)acc[nt][w * 4 + 3]};
      pk[nt][w][0] = lo.u; pk[nt][w][1] = hi.u;
    }
  f16x8 vreg[4];   // vreg[w].s[ii] = vote(w, ii, ch = tid)
  #pragma unroll
  for (int w = 0; w < 4; ++w) {
    unsigned int own0 = sub ? pk[1][w][0] : pk[0][w][0];
    unsigned int own1 = sub ? pk[1][w][1] : pk[0][w][1];
    unsigned int snd0 = sub ? pk[0][w][0] : pk[1][w][0];
    unsigned int snd1 = sub ? pk[0][w][1] : pk[1][w][1];
    unsigned int rc0 = (unsigned int)__shfl_xor((int)snd0, 32, 64);
    unsigned int rc1 = (unsigned int)__shfl_xor((int)snd1, 32, 64);
    f16x8u vv;
    vv.u32[0] = sub ? rc0 : own0;   // ii 0,1
    vv.u32[1] = sub ? rc1 : own1;   // ii 2,3
    vv.u32[2] = sub ? own0 : rc0;   // ii 4,5
    vv.u32[3] = sub ? own1 : rc1;   // ii 6,7
    vreg[w] = vv.v;
  }

  // ---------------- votesT: [w][grp=ch>>2][j=ch&3] f16x8, stride-68 rows ----------------
  __syncthreads();   // X region dead; votesT aliases it
  #pragma unroll
  for (int w = 0; w < 4; ++w)
    *(f16x8*)(smem + w * 4352 + (tid >> 2) * 68 + (tid & 3) * 16) = vreg[w];
  __syncthreads();

  // ---------------- routing: wave wid owns w = wid; NO barriers ----------------
  const int k = lane & 7;             // c-group slot; c = lane>>3
  // load this lane's 4 channels' votes, cvt to f32
  float vv[4][8];
  #pragma unroll
  for (int j = 0; j < 4; ++j) {
    f16x8u t8;
    t8.v = *(const f16x8*)(smem + wid * 4352 + lane * 68 + j * 16);
    #pragma unroll
    for (int ii = 0; ii < 8; ++ii) vv[j][ii] = (float)t8.v[ii];
  }
  const float4 bv4 = *(const float4*)(bias + lane * 4);
  const float bvj[4] = {bv4.x, bv4.y, bv4.z, bv4.w};

  float logit_k = 0.f;                // running logit(ii=k, c)
  float pre[4], scale = 0.f;

  #pragma unroll
  for (int rt = 0; rt < 3; ++rt) {
    float r[8];
    if (rt == 0) {
      #pragma unroll
      for (int i = 0; i < 8; ++i) r[i] = 0.125f;
    } else {
      // softmax over c (stride-8 lanes share k)
      float mx = logit_k;
      mx = fmaxf(mx, __shfl_xor(mx, 8, 64));
      mx = fmaxf(mx, __shfl_xor(mx, 16, 64));
      mx = fmaxf(mx, __shfl_xor(mx, 32, 64));
      float e = __expf(logit_k - mx);
      float den = e;
      den += __shfl_xor(den, 8, 64);
      den += __shfl_xor(den, 16, 64);
      den += __shfl_xor(den, 32, 64);
      float route_k = e / den;
      // broadcast: r[i] = route(ii=i, c) from lane (c<<3)|i
      int cbase = lane & 56;          // c<<3
      #pragma unroll
      for (int i = 0; i < 8; ++i) r[i] = __shfl(route_k, cbase | i, 64);
    }
    // weighted sum (lane-local)
    #pragma unroll
    for (int j = 0; j < 4; ++j) {
      float p = bvj[j];
      #pragma unroll
      for (int ii = 0; ii < 8; ++ii) p = fmaf(r[ii], vv[j][ii], p);
      pre[j] = p;
    }
    // squash scale: nsq over 32 atoms = 8-lane c-group reduce
    float nsq = pre[0] * pre[0] + pre[1] * pre[1] + pre[2] * pre[2] + pre[3] * pre[3];
    nsq += __shfl_xor(nsq, 1, 64);
    nsq += __shfl_xor(nsq, 2, 64);
    nsq += __shfl_xor(nsq, 4, 64);
    scale = sqrtf(nsq) / (1.f + nsq);
    if (rt < 2) {
      // agreement: dot8[ii] = sum over 32 atoms of vote*pre, then pick ii=k
      float dot8[8];
      #pragma unroll
      for (int ii = 0; ii < 8; ++ii) {
        float d = vv[0][ii] * pre[0];
        d = fmaf(vv[1][ii], pre[1], d);
        d = fmaf(vv[2][ii], pre[2], d);
        d = fmaf(vv[3][ii], pre[3], d);
        d += __shfl_xor(d, 1, 64);
        d += __shfl_xor(d, 2, 64);
        d += __shfl_xor(d, 4, 64);
        dot8[ii] = d;
      }
      // static select dot8[k], k = lane&7 (7 cndmask, no scratch)
      bool b0 = (k & 1), b1 = (k & 2), b2 = (k & 4);
      float e0 = b0 ? dot8[1] : dot8[0];
      float e1 = b0 ? dot8[3] : dot8[2];
      float e2 = b0 ? dot8[5] : dot8[4];
      float e3 = b0 ? dot8[7] : dot8[6];
      float f0 = b1 ? e1 : e0;
      float f1 = b1 ? e3 : e2;
      logit_k = fmaf(scale, b2 ? f1 : f0, logit_k);
    }
  }
  // final act = pre * scale; out[pos][ch], ch = lane*4+j -> coalesced float4
  const size_t pos = (size_t)((bb * 32 + h) * 32 + wq * 4 + wid);
  float4 o = make_float4(pre[0] * scale, pre[1] * scale, pre[2] * scale, pre[3] * scale);
  *(float4*)(out + pos * 256 + lane * 4) = o;
}

extern "C" void kernel_launch(void* const* d_in, const int* in_sizes, int n_in,
                              void* d_out, int out_size, void* d_ws, size_t ws_size,
                              hipStream_t stream) {
  (void)in_sizes; (void)n_in; (void)ws_size; (void)out_size;
  const float* inp  = (const float*)d_in[0];
  const float* W    = (const float*)d_in[1];
  const float* bv   = (const float*)d_in[2];
  float* out        = (float*)d_out;
  unsigned short* wsh = (unsigned short*)d_ws;   // 204800 B used

  hipLaunchKernelGGL(wprep_kernel, dim3(400), dim3(256), 0, stream, W, wsh);
  hipLaunchKernelGGL(capsconv_mfma_kernel, dim3(4096), dim3(256), 0, stream,
                     inp, wsh, bv, out);
}

// Round 14
// 54.882 us; speedup vs baseline: 1.0551x; 1.0551x over previous
//
#include <hip/hip_runtime.h>

// ConvCapsuleLayer r14: M=64 per block (8 w-pos) — each W bfrag feeds 2 MFMAs
// (mt=0,1) -> W L2 traffic halves vs r13 (819->410 MB). Conv = r6 geometry
// (acc[2][2], 64x64 per wave); routing = r13 barrier-free register scheme,
// wave owns 2 w-positions. 2048 blocks x 256 thr.

typedef __attribute__((ext_vector_type(2))) _Float16 f16x2;
typedef __attribute__((ext_vector_type(8))) _Float16 f16x8;
typedef __attribute__((ext_vector_type(16))) float f32x16;

union f16x8u { f16x8 v; f16x2 d[4]; unsigned short s[8]; unsigned int u32[4]; unsigned long long u[2]; };
union f16x2u { f16x2 v; unsigned int u; unsigned short s[2]; };

__device__ __forceinline__ unsigned short f2h(float x) {
  union { _Float16 h; unsigned short u; } v;
  v.h = (_Float16)x;
  return v.u;
}

// W[5][5][16][256] f32 -> wsh fp16 [khkw 25][ch 256][ia 16]
__global__ __launch_bounds__(256) void wprep_kernel(
    const float* __restrict__ W, unsigned short* __restrict__ wsh) {
  int t = blockIdx.x * 256 + threadIdx.x;      // 102400 total
  int khkw = t >> 12;
  int rem  = t & 4095;
  int ch = rem >> 4, ia = rem & 15;
  wsh[t] = f2h(W[khkw * 4096 + ia * 256 + ch]);
}

// LDS map (34816 B):
//   conv phase:  X fp16 [kh 5][ii 8, stride 400B][wl 12][ia 16] = 16000 B @0
//   transpose:   votesT fp16 [w 8, stride 4352][grp 64, stride 68][j 4][ii 8] @0
//                (aliases X; stride 68B -> bank stride 17, gcd(17,32)=1 -> <=2-way)
__global__ __launch_bounds__(256, 2) void capsconv_mfma_kernel(
    const float* __restrict__ inp,            // [16][32][32][8][16] f32
    const unsigned short* __restrict__ wsh,   // [25][256][16] fp16
    const float* __restrict__ bias,           // [256] f32
    float* __restrict__ out)                  // [16][32][32][256] f32
{
  __shared__ char smem[34816];
  const _Float16* wshh = (const _Float16*)wsh;

  const int tid  = threadIdx.x;
  const int wid  = tid >> 6;          // wave 0..3: conv ch quarter
  const int lane = tid & 63;
  const int sub  = lane >> 5;
  const int ln31 = lane & 31;

  const int bid = blockIdx.x;         // 2048 = ((bb*32 + h)*4 + wq)
  const int wq = bid & 3;
  const int h  = (bid >> 2) & 31;
  const int bb = bid >> 7;
  const int i_src  = bb >> 1;         // TF reshape scramble (verified r1/r4)
  const int b_base = (bb & 1) * 8;

  // ---------------- stage 5 X rows: [kh][ii][wl 12][ia], halo +-2 ----------------
  for (int e = tid; e < 1920; e += 256) {
    int kh = e / 384; int r1 = e - kh * 384;
    int ii = r1 / 48; int r2 = r1 - ii * 48;
    int wl = r2 >> 2; int iaq = r2 & 3;
    int hh = h + kh - 2;
    int wsrc = wq * 8 + wl - 2;
    float4 v = make_float4(0.f, 0.f, 0.f, 0.f);
    if ((unsigned)hh < 32u && (unsigned)wsrc < 32u)
      v = *(const float4*)(inp +
          ((((size_t)(b_base + ii) * 32 + hh) * 32 + wsrc) * 8 + i_src) * 16 + iaq * 4);
    union { _Float16 hx[4]; unsigned long long u; } pkk;
    pkk.hx[0] = (_Float16)v.x; pkk.hx[1] = (_Float16)v.y;
    pkk.hx[2] = (_Float16)v.z; pkk.hx[3] = (_Float16)v.w;
    *(unsigned long long*)(smem + kh * 3200 + ii * 400 + wl * 32 + iaq * 8) = pkk.u;
  }
  __syncthreads();

  // ---------------- conv: 25 taps, acc[2][2]; bfrag reused across mt ----------------
  f32x16 acc[2][2];
  #pragma unroll
  for (int mt = 0; mt < 2; ++mt)
    #pragma unroll
    for (int nt = 0; nt < 2; ++nt)
      #pragma unroll
      for (int e = 0; e < 16; ++e) acc[mt][nt][e] = 0.f;

  const char* aBase = smem + (ln31 & 7) * 400 + (ln31 >> 3) * 32 + sub * 16;
  const _Float16* bBase = wshh + (wid * 64 + ln31) * 16 + sub * 8;

  #pragma unroll
  for (int kh = 0; kh < 5; ++kh) {
    f16x8 af0[5], af1[5], bf0[5], bf1[5];
    #pragma unroll
    for (int kw = 0; kw < 5; ++kw) {
      af0[kw] = *(const f16x8*)(aBase + kh * 3200 + kw * 32);            // rows mt=0
      af1[kw] = *(const f16x8*)(aBase + kh * 3200 + (kw + 4) * 32);      // rows mt=1 (w_local+4)
      bf0[kw] = *(const f16x8*)(bBase + (size_t)(kh * 5 + kw) * 4096);
      bf1[kw] = *(const f16x8*)(bBase + (size_t)(kh * 5 + kw) * 4096 + 512);
    }
    #pragma unroll
    for (int kw = 0; kw < 5; ++kw) {
      acc[0][0] = __builtin_amdgcn_mfma_f32_32x32x16_f16(af0[kw], bf0[kw], acc[0][0], 0, 0, 0);
      acc[0][1] = __builtin_amdgcn_mfma_f32_32x32x16_f16(af0[kw], bf1[kw], acc[0][1], 0, 0, 0);
      acc[1][0] = __builtin_amdgcn_mfma_f32_32x32x16_f16(af1[kw], bf0[kw], acc[1][0], 0, 0, 0);
      acc[1][1] = __builtin_amdgcn_mfma_f32_32x32x16_f16(af1[kw], bf1[kw], acc[1][1], 0, 0, 0);
    }
  }

  // ---------------- pack acc -> fp16; assemble vreg via lane^32 shfl ----------------
  // acc[mt][nt][q*4+t] = vote(w = mt*4+q, ii = t+4sub, ch = wid*64+nt*32+ln31).
  unsigned int pk[2][2][4][2];
  #pragma unroll
  for (int mt = 0; mt < 2; ++mt)
    #pragma unroll
    for (int nt = 0; nt < 2; ++nt)
      #pragma unroll
      for (int q = 0; q < 4; ++q) {
        f16x2u lo, hi;
        lo.v = f16x2{(_Float16)acc[mt][nt][q * 4 + 0], (_Float16)acc[mt][nt][q * 4 + 1]};
        hi.v = f16x2{(_Float16)acc[mt][nt][q * 4 + 2], (_Float16)acc[mt][nt][q * 4 + 3]};
        pk[mt][nt][q][0] = lo.u; pk[mt][nt][q][1] = hi.u;
      }
  f16x8 vreg[8];   // vreg[w].s[ii] = vote(w, ii, ch = tid)
  #pragma unroll
  for (int mt = 0; mt < 2; ++mt)
    #pragma unroll
    for (int q = 0; q < 4; ++q) {
      unsigned int own0 = sub ? pk[mt][1][q][0] : pk[mt][0][q][0];
      unsigned int own1 = sub ? pk[mt][1][q][1] : pk[mt][0][q][1];
      unsigned int snd0 = sub ? pk[mt][0][q][0] : pk[mt][1][q][0];
      unsigned int snd1 = sub ? pk[mt][0][q][1] : pk[mt][1][q][1];
      unsigned int rc0 = (unsigned int)__shfl_xor((int)snd0, 32, 64);
      unsigned int rc1 = (unsigned int)__shfl_xor((int)snd1, 32, 64);
      f16x8u vv;
      vv.u32[0] = sub ? rc0 : own0;   // ii 0,1
      vv.u32[1] = sub ? rc1 : own1;   // ii 2,3
      vv.u32[2] = sub ? own0 : rc0;   // ii 4,5
      vv.u32[3] = sub ? own1 : rc1;   // ii 6,7
      vreg[mt * 4 + q] = vv.v;
    }

  // ---------------- votesT: [w 8][grp=ch>>2][j=ch&3] f16x8, stride-68 rows ----------------
  __syncthreads();   // X region dead; votesT aliases it
  #pragma unroll
  for (int w = 0; w < 8; ++w)
    *(f16x8*)(smem + w * 4352 + (tid >> 2) * 68 + (tid & 3) * 16) = vreg[w];
  __syncthreads();

  // ---------------- routing: wave wid owns w = wid*2+p (p=0,1); NO barriers ----------------
  const int k = lane & 7;             // c-group slot; c = lane>>3
  float vv[2][4][8];
  #pragma unroll
  for (int p = 0; p < 2; ++p)
    #pragma unroll
    for (int j = 0; j < 4; ++j) {
      f16x8u t8;
      t8.v = *(const f16x8*)(smem + (wid * 2 + p) * 4352 + lane * 68 + j * 16);
      #pragma unroll
      for (int ii = 0; ii < 8; ++ii) vv[p][j][ii] = (float)t8.v[ii];
    }
  const float4 bv4 = *(const float4*)(bias + lane * 4);
  const float bvj[4] = {bv4.x, bv4.y, bv4.z, bv4.w};

  float logit_k[2] = {0.f, 0.f};
  float pre[2][4], scale[2] = {0.f, 0.f};

  #pragma unroll
  for (int rt = 0; rt < 3; ++rt) {
    #pragma unroll
    for (int p = 0; p < 2; ++p) {
      float r[8];
      if (rt == 0) {
        #pragma unroll
        for (int i = 0; i < 8; ++i) r[i] = 0.125f;
      } else {
        float mx = logit_k[p];
        mx = fmaxf(mx, __shfl_xor(mx, 8, 64));
        mx = fmaxf(mx, __shfl_xor(mx, 16, 64));
        mx = fmaxf(mx, __shfl_xor(mx, 32, 64));
        float e = __expf(logit_k[p] - mx);
        float den = e;
        den += __shfl_xor(den, 8, 64);
        den += __shfl_xor(den, 16, 64);
        den += __shfl_xor(den, 32, 64);
        float route_k = e / den;
        int cbase = lane & 56;          // c<<3
        #pragma unroll
        for (int i = 0; i < 8; ++i) r[i] = __shfl(route_k, cbase | i, 64);
      }
      #pragma unroll
      for (int j = 0; j < 4; ++j) {
        float pp = bvj[j];
        #pragma unroll
        for (int ii = 0; ii < 8; ++ii) pp = fmaf(r[ii], vv[p][j][ii], pp);
        pre[p][j] = pp;
      }
      float nsq = pre[p][0] * pre[p][0] + pre[p][1] * pre[p][1] +
                  pre[p][2] * pre[p][2] + pre[p][3] * pre[p][3];
      nsq += __shfl_xor(nsq, 1, 64);
      nsq += __shfl_xor(nsq, 2, 64);
      nsq += __shfl_xor(nsq, 4, 64);
      scale[p] = sqrtf(nsq) / (1.f + nsq);
      if (rt < 2) {
        float dot8[8];
        #pragma unroll
        for (int ii = 0; ii < 8; ++ii) {
          float d = vv[p][0][ii] * pre[p][0];
          d = fmaf(vv[p][1][ii], pre[p][1], d);
          d = fmaf(vv[p][2][ii], pre[p][2], d);
          d = fmaf(vv[p][3][ii], pre[p][3], d);
          d += __shfl_xor(d, 1, 64);
          d += __shfl_xor(d, 2, 64);
          d += __shfl_xor(d, 4, 64);
          dot8[ii] = d;
        }
        bool b0 = (k & 1), b1 = (k & 2), b2 = (k & 4);
        float e0 = b0 ? dot8[1] : dot8[0];
        float e1 = b0 ? dot8[3] : dot8[2];
        float e2 = b0 ? dot8[5] : dot8[4];
        float e3 = b0 ? dot8[7] : dot8[6];
        float f0 = b1 ? e1 : e0;
        float f1 = b1 ? e3 : e2;
        logit_k[p] = fmaf(scale[p], b2 ? f1 : f0, logit_k[p]);
      }
    }
  }
  // final act = pre * scale; coalesced float4 per position
  const size_t base8 = (size_t)((bb * 32 + h) * 32 + wq * 8);
  #pragma unroll
  for (int p = 0; p < 2; ++p) {
    float4 o = make_float4(pre[p][0] * scale[p], pre[p][1] * scale[p],
                           pre[p][2] * scale[p], pre[p][3] * scale[p]);
    *(float4*)(out + (base8 + wid * 2 + p) * 256 + lane * 4) = o;
  }
}

extern "C" void kernel_launch(void* const* d_in, const int* in_sizes, int n_in,
                              void* d_out, int out_size, void* d_ws, size_t ws_size,
                              hipStream_t stream) {
  (void)in_sizes; (void)n_in; (void)ws_size; (void)out_size;
  const float* inp  = (const float*)d_in[0];
  const float* W    = (const float*)d_in[1];
  const float* bv   = (const float*)d_in[2];
  float* out        = (float*)d_out;
  unsigned short* wsh = (unsigned short*)d_ws;   // 204800 B used

  hipLaunchKernelGGL(wprep_kernel, dim3(400), dim3(256), 0, stream, W, wsh);
  hipLaunchKernelGGL(capsconv_mfma_kernel, dim3(2048), dim3(256), 0, stream,
                     inp, wsh, bv, out);
}

// Round 15
// 49.530 us; speedup vs baseline: 1.1691x; 1.1081x over previous
//
#include <hip/hip_runtime.h>

// ConvCapsuleLayer r15: cross-lane traffic moved off the DS pipe.
// - nsq/agreement reductions via DPP add trees (quad_perm + row_half_mirror): 0 DS ops.
// - softmax xor8 via DPP row_ror:8; only xor16/32 remain as shfl.
// - votesT written directly as b64 per lane (lanes L/L^32 hold same ch) -> the 16
//   xor32 pack shuffles are deleted. Stride 72B (8-aligned, <=4-way banks).
// Conv = r14 geometry (M=64, acc[2][2], bfrag reused across mt). 2048 blocks.

typedef __attribute__((ext_vector_type(2))) _Float16 f16x2;
typedef __attribute__((ext_vector_type(8))) _Float16 f16x8;
typedef __attribute__((ext_vector_type(16))) float f32x16;

union f16x8u { f16x8 v; f16x2 d[4]; unsigned short s[8]; unsigned int u32[4]; unsigned long long u[2]; };
union f16x2u { f16x2 v; unsigned int u; unsigned short s[2]; };

__device__ __forceinline__ unsigned short f2h(float x) {
  union { _Float16 h; unsigned short u; } v;
  v.h = (_Float16)x;
  return v.u;
}

template<int CTRL>
__device__ __forceinline__ float dpp_mov(float x) {
  return __builtin_bit_cast(float, __builtin_amdgcn_update_dpp(
      0, __builtin_bit_cast(int, x), CTRL, 0xF, 0xF, true));
}
// sum over 8-lane c-group (lanes sharing lane>>3): xor1, xor2, mirror(^7)
__device__ __forceinline__ float sum8_dpp(float x) {
  x += dpp_mov<0xB1>(x);    // quad_perm [1,0,3,2]  : ^1
  x += dpp_mov<0x4E>(x);    // quad_perm [2,3,0,1]  : ^2
  x += dpp_mov<0x141>(x);   // row_half_mirror      : ^7 (other quad of the 8)
  return x;
}

// W[5][5][16][256] f32 -> wsh fp16 [khkw 25][ch 256][ia 16]
__global__ __launch_bounds__(256) void wprep_kernel(
    const float* __restrict__ W, unsigned short* __restrict__ wsh) {
  int t = blockIdx.x * 256 + threadIdx.x;      // 102400 total
  int khkw = t >> 12;
  int rem  = t & 4095;
  int ch = rem >> 4, ia = rem & 15;
  wsh[t] = f2h(W[khkw * 4096 + ia * 256 + ch]);
}

// LDS map (36864 B):
//   conv phase:  X fp16 [kh 5][ii 8, stride 400B][wl 12][ia 16] = 16000 B @0
//   transpose:   votesT fp16 [w 8, stride 4608][grp 64, stride 72][j 4][ii 8] @0
//                (aliases X; 72B = 8-aligned for b64 writes, 18-word bank stride)
__global__ __launch_bounds__(256, 2) void capsconv_mfma_kernel(
    const float* __restrict__ inp,            // [16][32][32][8][16] f32
    const unsigned short* __restrict__ wsh,   // [25][256][16] fp16
    const float* __restrict__ bias,           // [256] f32
    float* __restrict__ out)                  // [16][32][32][256] f32
{
  __shared__ char smem[36864];
  const _Float16* wshh = (const _Float16*)wsh;

  const int tid  = threadIdx.x;
  const int wid  = tid >> 6;          // wave 0..3: conv ch quarter
  const int lane = tid & 63;
  const int sub  = lane >> 5;
  const int ln31 = lane & 31;

  const int bid = blockIdx.x;         // 2048 = ((bb*32 + h)*4 + wq)
  const int wq = bid & 3;
  const int h  = (bid >> 2) & 31;
  const int bb = bid >> 7;
  const int i_src  = bb >> 1;         // TF reshape scramble (verified r1/r4)
  const int b_base = (bb & 1) * 8;

  // ---------------- stage 5 X rows: [kh][ii][wl 12][ia], halo +-2 ----------------
  for (int e = tid; e < 1920; e += 256) {
    int kh = e / 384; int r1 = e - kh * 384;
    int ii = r1 / 48; int r2 = r1 - ii * 48;
    int wl = r2 >> 2; int iaq = r2 & 3;
    int hh = h + kh - 2;
    int wsrc = wq * 8 + wl - 2;
    float4 v = make_float4(0.f, 0.f, 0.f, 0.f);
    if ((unsigned)hh < 32u && (unsigned)wsrc < 32u)
      v = *(const float4*)(inp +
          ((((size_t)(b_base + ii) * 32 + hh) * 32 + wsrc) * 8 + i_src) * 16 + iaq * 4);
    union { _Float16 hx[4]; unsigned long long u; } pkk;
    pkk.hx[0] = (_Float16)v.x; pkk.hx[1] = (_Float16)v.y;
    pkk.hx[2] = (_Float16)v.z; pkk.hx[3] = (_Float16)v.w;
    *(unsigned long long*)(smem + kh * 3200 + ii * 400 + wl * 32 + iaq * 8) = pkk.u;
  }
  __syncthreads();

  // ---------------- conv: 25 taps, acc[2][2]; bfrag reused across mt ----------------
  f32x16 acc[2][2];
  #pragma unroll
  for (int mt = 0; mt < 2; ++mt)
    #pragma unroll
    for (int nt = 0; nt < 2; ++nt)
      #pragma unroll
      for (int e = 0; e < 16; ++e) acc[mt][nt][e] = 0.f;

  const char* aBase = smem + (ln31 & 7) * 400 + (ln31 >> 3) * 32 + sub * 16;
  const _Float16* bBase = wshh + (wid * 64 + ln31) * 16 + sub * 8;

  #pragma unroll
  for (int kh = 0; kh < 5; ++kh) {
    #pragma unroll
    for (int kw = 0; kw < 5; ++kw) {
      f16x8 af0 = *(const f16x8*)(aBase + kh * 3200 + kw * 32);          // rows mt=0
      f16x8 af1 = *(const f16x8*)(aBase + kh * 3200 + (kw + 4) * 32);    // rows mt=1
      f16x8 bf0 = *(const f16x8*)(bBase + (size_t)(kh * 5 + kw) * 4096);
      f16x8 bf1 = *(const f16x8*)(bBase + (size_t)(kh * 5 + kw) * 4096 + 512);
      acc[0][0] = __builtin_amdgcn_mfma_f32_32x32x16_f16(af0, bf0, acc[0][0], 0, 0, 0);
      acc[0][1] = __builtin_amdgcn_mfma_f32_32x32x16_f16(af0, bf1, acc[0][1], 0, 0, 0);
      acc[1][0] = __builtin_amdgcn_mfma_f32_32x32x16_f16(af1, bf0, acc[1][0], 0, 0, 0);
      acc[1][1] = __builtin_amdgcn_mfma_f32_32x32x16_f16(af1, bf1, acc[1][1], 0, 0, 0);
    }
  }

  // ---------------- votesT: direct b64 writes, no shuffles ----------------
  // acc[mt][nt][q*4+t] = vote(w=mt*4+q, ii=t+4sub, ch=wid*64+nt*32+ln31):
  // each lane writes its own 4-ii half (sub selects b64 half of the 8-ii row).
  __syncthreads();   // X region dead; votesT aliases it
  #pragma unroll
  for (int mt = 0; mt < 2; ++mt)
    #pragma unroll
    for (int nt = 0; nt < 2; ++nt) {
      int ch = wid * 64 + nt * 32 + ln31;
      char* base = smem + (ch >> 2) * 72 + (ch & 3) * 16 + sub * 8;
      #pragma unroll
      for (int q = 0; q < 4; ++q) {
        f16x2u lo, hi;
        lo.v = f16x2{(_Float16)acc[mt][nt][q * 4 + 0], (_Float16)acc[mt][nt][q * 4 + 1]};
        hi.v = f16x2{(_Float16)acc[mt][nt][q * 4 + 2], (_Float16)acc[mt][nt][q * 4 + 3]};
        unsigned long long u = (unsigned long long)lo.u |
                               ((unsigned long long)hi.u << 32);
        *(unsigned long long*)(base + (mt * 4 + q) * 4608) = u;
      }
    }
  __syncthreads();

  // ---------------- routing: wave wid owns w = wid*2+p; DPP reductions ----------------
  const int k = lane & 7;             // c-group slot; c = lane>>3
  float vv[2][4][8];
  #pragma unroll
  for (int p = 0; p < 2; ++p)
    #pragma unroll
    for (int j = 0; j < 4; ++j) {
      f16x8u t8;
      t8.v = *(const f16x8*)(smem + (wid * 2 + p) * 4608 + lane * 72 + j * 16);
      #pragma unroll
      for (int ii = 0; ii < 8; ++ii) vv[p][j][ii] = (float)t8.v[ii];
    }
  const float4 bv4 = *(const float4*)(bias + lane * 4);
  const float bvj[4] = {bv4.x, bv4.y, bv4.z, bv4.w};

  float logit_k[2] = {0.f, 0.f};
  float pre[2][4], scale[2] = {0.f, 0.f};

  #pragma unroll
  for (int rt = 0; rt < 3; ++rt) {
    #pragma unroll
    for (int p = 0; p < 2; ++p) {
      float r[8];
      if (rt == 0) {
        #pragma unroll
        for (int i = 0; i < 8; ++i) r[i] = 0.125f;
      } else {
        // softmax over c: lanes stride 8 -> xor8 via DPP ror8, xor16/32 via shfl
        float mx = logit_k[p];
        mx = fmaxf(mx, dpp_mov<0x128>(mx));             // row_ror:8 = ^8
        mx = fmaxf(mx, __shfl_xor(mx, 16, 64));
        mx = fmaxf(mx, __shfl_xor(mx, 32, 64));
        float e = __expf(logit_k[p] - mx);
        float den = e;
        den += dpp_mov<0x128>(den);
        den += __shfl_xor(den, 16, 64);
        den += __shfl_xor(den, 32, 64);
        float route_k = e / den;
        int cbase = lane & 56;          // c<<3
        #pragma unroll
        for (int i = 0; i < 8; ++i) r[i] = __shfl(route_k, cbase | i, 64);
      }
      #pragma unroll
      for (int j = 0; j < 4; ++j) {
        float pp = bvj[j];
        #pragma unroll
        for (int ii = 0; ii < 8; ++ii) pp = fmaf(r[ii], vv[p][j][ii], pp);
        pre[p][j] = pp;
      }
      // squash scale: nsq over 32 atoms = 8-lane c-group DPP reduce
      float nsq = pre[p][0] * pre[p][0] + pre[p][1] * pre[p][1] +
                  pre[p][2] * pre[p][2] + pre[p][3] * pre[p][3];
      nsq = sum8_dpp(nsq);
      scale[p] = sqrtf(nsq) / (1.f + nsq);
      if (rt < 2) {
        // agreement: dot8[ii] over 32 atoms via DPP trees (0 DS ops)
        float dot8[8];
        #pragma unroll
        for (int ii = 0; ii < 8; ++ii) {
          float d = vv[p][0][ii] * pre[p][0];
          d = fmaf(vv[p][1][ii], pre[p][1], d);
          d = fmaf(vv[p][2][ii], pre[p][2], d);
          d = fmaf(vv[p][3][ii], pre[p][3], d);
          dot8[ii] = sum8_dpp(d);
        }
        bool b0 = (k & 1), b1 = (k & 2), b2 = (k & 4);
        float e0 = b0 ? dot8[1] : dot8[0];
        float e1 = b0 ? dot8[3] : dot8[2];
        float e2 = b0 ? dot8[5] : dot8[4];
        float e3 = b0 ? dot8[7] : dot8[6];
        float f0 = b1 ? e1 : e0;
        float f1 = b1 ? e3 : e2;
        logit_k[p] = fmaf(scale[p], b2 ? f1 : f0, logit_k[p]);
      }
    }
  }
  // final act = pre * scale; coalesced float4 per position
  const size_t base8 = (size_t)((bb * 32 + h) * 32 + wq * 8);
  #pragma unroll
  for (int p = 0; p < 2; ++p) {
    float4 o = make_float4(pre[p][0] * scale[p], pre[p][1] * scale[p],
                           pre[p][2] * scale[p], pre[p][3] * scale[p]);
    *(float4*)(out + (base8 + wid * 2 + p) * 256 + lane * 4) = o;
  }
}

extern "C" void kernel_launch(void* const* d_in, const int* in_sizes, int n_in,
                              void* d_out, int out_size, void* d_ws, size_t ws_size,
                              hipStream_t stream) {
  (void)in_sizes; (void)n_in; (void)ws_size; (void)out_size;
  const float* inp  = (const float*)d_in[0];
  const float* W    = (const float*)d_in[1];
  const float* bv   = (const float*)d_in[2];
  float* out        = (float*)d_out;
  unsigned short* wsh = (unsigned short*)d_ws;   // 204800 B used

  hipLaunchKernelGGL(wprep_kernel, dim3(400), dim3(256), 0, stream, W, wsh);
  hipLaunchKernelGGL(capsconv_mfma_kernel, dim3(2048), dim3(256), 0, stream,
                     inp, wsh, bv, out);
}